// Round 27
// baseline (569.337 us; speedup 1.0000x reference)
//
#include <hip/hip_runtime.h>
#include <hip/hip_bf16.h>

#define BB   16
#define SS   8192
#define DD   128
#define HH   256
#define NTOK (BB * SS)
#define TM   64
#define THREADS 256
#define LRATE 0.1f
#define EPSV  1e-5f
#define XCST 264   // XC stride in shorts
#define RST  264   // Rb stride
// T2 XOR swizzle: permutes 16B blocks within each row's 128-short window per (row&7).
// Applied to EVERY XC/Rb access -> bit-identical values, conflict-free b128 reads.
#define SW(row, col) ((col) ^ (((row) & 7) << 3))

typedef short  bfrag __attribute__((ext_vector_type(8)));
typedef float  f32x4 __attribute__((ext_vector_type(4)));
typedef unsigned short u16;

__device__ __forceinline__ u16 f2bf(float x) {
    unsigned u = __float_as_uint(x);
    unsigned r = (u + 0x7FFFu + ((u >> 16) & 1u)) >> 16;   // RTN-even
    return (u16)r;
}
__device__ __forceinline__ unsigned pkbf(float lo, float hi) {
    __hip_bfloat162 h2 = __float22bfloat162_rn(make_float2(lo, hi));
    unsigned u; __builtin_memcpy(&u, &h2, 4); return u;
}
__device__ __forceinline__ float blo(unsigned u) { return __uint_as_float(u << 16); }
__device__ __forceinline__ float bhi(unsigned u) { return __uint_as_float(u & 0xffff0000u); }
__device__ __forceinline__ float b2f(u16 u)      { return __uint_as_float((unsigned)u << 16); }
__device__ __forceinline__ unsigned avgpk(unsigned a, unsigned b) {
    return pkbf(0.5f * (blo(a) + blo(b)), 0.5f * (bhi(a) + bhi(b)));
}

// ---- weight prep: fp32 [K][N] -> bf16 transposed [N][K]; W2t/Wg2t K-permuted within 32-groups ----
__global__ void prep_weights(const float* __restrict__ W1, const float* __restrict__ W2,
                             const float* __restrict__ Wg1, const float* __restrict__ Wg2,
                             u16* __restrict__ wsw) {
    int i = blockIdx.x * 256 + threadIdx.x;   // 0 .. 163839
    if (i < 32768) { int n = i >> 7, k = i & 127; wsw[i] = f2bf(W1[k * 256 + n]); return; }
    i -= 32768;
    if (i < 32768) {
        int n = i >> 8, k = i & 255;
        int m = k & 31;
        int kl = (k & ~31) | ((m & 1) ? ((m >> 1) + 16) : (m >> 1));
        wsw[32768 + n * 256 + k] = f2bf(W2[kl * 128 + n]);
        return;
    }
    i -= 32768;
    if (i < 65536) { int n = i >> 8, k = i & 255; wsw[65536 + n * 256 + k] = f2bf(Wg1[k * 256 + n]); return; }
    i -= 65536;
    {
        int n = i >> 8, k = i & 255;
        int m = k & 31;
        int kl = (k & ~31) | ((m & 1) ? ((m >> 1) + 16) : (m >> 1));
        wsw[131072 + n * 256 + k] = f2bf(Wg2[kl * 128 + n]);
    }
}

template<bool BIN, bool BOUT>
__global__ __launch_bounds__(THREADS, 2)
void refine_iter(const void* __restrict__ curv, const float* __restrict__ emb,
                 void* __restrict__ outv,
                 const u16* __restrict__ w1t, const u16* __restrict__ w2t,
                 const u16* __restrict__ wg1t, const u16* __restrict__ wg2t,
                 const float* __restrict__ b1, const float* __restrict__ lng,
                 const float* __restrict__ lnb, const float* __restrict__ b2,
                 const float* __restrict__ bg1, const float* __restrict__ bg2)
{
    const float* curf = (const float*)curv;
    const u16*   curb = (const u16*)curv;

    __shared__ __align__(16) u16 XC[TM][XCST];   // [x|ctx] -> H (K-permuted), XOR-swizzled
    __shared__ __align__(16) u16 Rb[TM][RST];    // R (K-permuted), XOR-swizzled
    __shared__ float red1[TM][4];
    __shared__ float red2[TM][4];

    const int t    = threadIdx.x;
    const int nwg  = (int)gridDim.x;
    const int cpx  = nwg >> 3;
    const int bid  = (int)blockIdx.x;
    const int swz  = (bid & 7) * cpx + (bid >> 3);
    const int g0   = swz * TM;
    const int lane = t & 63;
    const int wid  = t >> 6;
    const int l16  = lane & 15;
    const int lk8  = (lane >> 4) * 8;
    const int l4   = (lane >> 4) * 4;
    const int nAC  = wid * 64;
    const int nBD  = wid * 32;

    // ---- stage x tile + context tile, 8 shorts/lane/iter (swizzled writes) ----
    #pragma unroll
    for (int k = 0; k < 4; ++k) {
        const int f = t + k * THREADS;
        const int m = f >> 4;
        const int o = (f & 15) * 8;
        const int gt = g0 + m;
        const int s  = gt & (SS - 1);
        const int rowbase = gt - s;
        const int sp = (s == 0) ? 1 : s - 1;
        const int sn = (s == SS - 1) ? (SS - 2) : s + 1;
        if (BIN) {
            const uint4 xq = *(const uint4*)(curb + (size_t)gt * DD + o);
            *(uint4*)&XC[m][SW(m, o)] = xq;
            const uint4 aq = *(const uint4*)(curb + (size_t)(rowbase + sp) * DD + o);
            const uint4 bq = *(const uint4*)(curb + (size_t)(rowbase + sn) * DD + o);
            uint4 cq;
            cq.x = avgpk(aq.x, bq.x); cq.y = avgpk(aq.y, bq.y);
            cq.z = avgpk(aq.z, bq.z); cq.w = avgpk(aq.w, bq.w);
            *(uint4*)&XC[m][SW(m, 128 + o)] = cq;
        } else {
            const float4 xv0 = *(const float4*)(curf + (size_t)gt * DD + o);
            const float4 xv1 = *(const float4*)(curf + (size_t)gt * DD + o + 4);
            const float4 av0 = *(const float4*)(curf + (size_t)(rowbase + sp) * DD + o);
            const float4 av1 = *(const float4*)(curf + (size_t)(rowbase + sp) * DD + o + 4);
            const float4 bv0 = *(const float4*)(curf + (size_t)(rowbase + sn) * DD + o);
            const float4 bv1 = *(const float4*)(curf + (size_t)(rowbase + sn) * DD + o + 4);
            uint4 xq;
            xq.x = pkbf(xv0.x, xv0.y); xq.y = pkbf(xv0.z, xv0.w);
            xq.z = pkbf(xv1.x, xv1.y); xq.w = pkbf(xv1.z, xv1.w);
            *(uint4*)&XC[m][SW(m, o)] = xq;
            uint4 cq;
            cq.x = pkbf(0.5f * (av0.x + bv0.x), 0.5f * (av0.y + bv0.y));
            cq.y = pkbf(0.5f * (av0.z + bv0.z), 0.5f * (av0.w + bv0.w));
            cq.z = pkbf(0.5f * (av1.x + bv1.x), 0.5f * (av1.y + bv1.y));
            cq.w = pkbf(0.5f * (av1.z + bv1.z), 0.5f * (av1.w + bv1.w));
            *(uint4*)&XC[m][SW(m, 128 + o)] = cq;
        }
    }
    __syncthreads();   // (1) stage barrier

    // ---- cp from LDS x-region (before barrier 2; swizzled read) ----
    float cp[4][2][4];
    #pragma unroll
    for (int rt = 0; rt < 4; ++rt)
        #pragma unroll
        for (int ct = 0; ct < 2; ++ct)
            #pragma unroll
            for (int r = 0; r < 4; ++r) {
                const int row = rt * 16 + l4 + r;
                cp[rt][ct][r] = b2f(XC[row][SW(row, nBD + ct * 16 + l16)]);
            }

    const f32x4 zf = {0.f, 0.f, 0.f, 0.f};
    float mu[4][4], rs[4][4];

    // ======== FUSED region 1: A (X@W1 -> accA) + C ([X|C]@Wg1 -> R early) ========
    f32x4 accA[4][4];
    #pragma unroll
    for (int rt = 0; rt < 4; ++rt)
        #pragma unroll
        for (int ct = 0; ct < 4; ++ct) accA[rt][ct] = zf;

    #pragma unroll
    for (int h = 0; h < 2; ++h) {
        bfrag wb[8];
        #pragma unroll
        for (int i = 0; i < 2; ++i)
            #pragma unroll
            for (int ks = 0; ks < 4; ++ks)
                wb[i * 4 + ks] = *(const bfrag*)(w1t + (size_t)(nAC + (h * 2 + i) * 16 + l16) * 128 + ks * 32 + lk8);
        __builtin_amdgcn_sched_barrier(0);
        __builtin_amdgcn_s_setprio(1);
        #pragma unroll
        for (int ks = 0; ks < 4; ++ks) {
            bfrag af[4];
            #pragma unroll
            for (int rt = 0; rt < 4; ++rt)
                af[rt] = *(const bfrag*)&XC[rt * 16 + l16][SW(l16, ks * 32 + lk8)];
            #pragma unroll
            for (int i = 0; i < 2; ++i)
                #pragma unroll
                for (int rt = 0; rt < 4; ++rt)
                    accA[rt][h * 2 + i] = __builtin_amdgcn_mfma_f32_16x16x32_bf16(af[rt], wb[i * 4 + ks], accA[rt][h * 2 + i], 0, 0, 0);
        }
        __builtin_amdgcn_s_setprio(0);
    }
    #pragma unroll
    for (int h = 0; h < 2; ++h) {
        f32x4 accC[4][2];
        #pragma unroll
        for (int rt = 0; rt < 4; ++rt) { accC[rt][0] = zf; accC[rt][1] = zf; }
        #pragma unroll
        for (int kh = 0; kh < 2; ++kh) {
            bfrag wb[8];
            #pragma unroll
            for (int i = 0; i < 2; ++i)
                #pragma unroll
                for (int ks2 = 0; ks2 < 4; ++ks2)
                    wb[i * 4 + ks2] = *(const bfrag*)(wg1t + (size_t)(nAC + (h * 2 + i) * 16 + l16) * 256 + (kh * 4 + ks2) * 32 + lk8);
            __builtin_amdgcn_sched_barrier(0);
            __builtin_amdgcn_s_setprio(1);
            #pragma unroll
            for (int ks2 = 0; ks2 < 4; ++ks2) {
                const int ks = kh * 4 + ks2;
                bfrag af[4];
                #pragma unroll
                for (int rt = 0; rt < 4; ++rt)
                    af[rt] = *(const bfrag*)&XC[rt * 16 + l16][SW(l16, ks * 32 + lk8)];
                #pragma unroll
                for (int i = 0; i < 2; ++i)
                    #pragma unroll
                    for (int rt = 0; rt < 4; ++rt)
                        accC[rt][i] = __builtin_amdgcn_mfma_f32_16x16x32_bf16(af[rt], wb[i * 4 + ks2], accC[rt][i], 0, 0, 0);
            }
            __builtin_amdgcn_s_setprio(0);
        }
        const float bga = bg1[nAC + (h * 2) * 16 + l16];
        const float bgb = bg1[nAC + (h * 2 + 1) * 16 + l16];
        #pragma unroll
        for (int rt = 0; rt < 4; ++rt)
            #pragma unroll
            for (int r = 0; r < 4; ++r) {
                const float r0v = fmaxf(accC[rt][0][r] + bga, 0.f);
                const float r1v = fmaxf(accC[rt][1][r] + bgb, 0.f);
                const int row = rt * 16 + l4 + r;
                *(unsigned*)&Rb[row][SW(row, nAC + h * 32 + 2 * l16)] = pkbf(r0v, r1v);
            }
    }

    // ---- bias + LN stats on accA ----
    #pragma unroll
    for (int ct = 0; ct < 4; ++ct) {
        const float bb = b1[nAC + ct * 16 + l16];
        #pragma unroll
        for (int rt = 0; rt < 4; ++rt)
            #pragma unroll
            for (int r = 0; r < 4; ++r) accA[rt][ct][r] += bb;
    }
    #pragma unroll
    for (int rt = 0; rt < 4; ++rt)
        #pragma unroll
        for (int r = 0; r < 4; ++r) {
            float a = 0.f, q = 0.f;
            #pragma unroll
            for (int ct = 0; ct < 4; ++ct) {
                const float v = accA[rt][ct][r];
                a += v; q += v * v;
            }
            #pragma unroll
            for (int m = 1; m <= 8; m <<= 1) {
                a += __shfl_xor(a, m);
                q += __shfl_xor(q, m);
            }
            if (l16 == 0) {
                red1[rt * 16 + l4 + r][wid] = a;
                red2[rt * 16 + l4 + r][wid] = q;
            }
        }
    __syncthreads();   // (2) LN barrier
    #pragma unroll
    for (int rt = 0; rt < 4; ++rt)
        #pragma unroll
        for (int r = 0; r < 4; ++r) {
            const int row = rt * 16 + l4 + r;
            const float4 s1v = *(const float4*)&red1[row][0];
            const float4 s2v = *(const float4*)&red2[row][0];
            const float s1 = s1v.x + s1v.y + s1v.z + s1v.w;
            const float s2 = s2v.x + s2v.y + s2v.z + s2v.w;
            const float m_ = s1 * (1.f / (float)HH);
            mu[rt][r] = m_;
            rs[rt][r] = rsqrtf(s2 * (1.f / (float)HH) - m_ * m_ + EPSV);
        }

    // ---- write H -> XC, K-permuted single u32 store (swizzled) ----
    #pragma unroll
    for (int cp2 = 0; cp2 < 2; ++cp2) {
        const float g0v = lng[nAC + (2 * cp2) * 16 + l16],     b0v = lnb[nAC + (2 * cp2) * 16 + l16];
        const float g1v = lng[nAC + (2 * cp2 + 1) * 16 + l16], b1v = lnb[nAC + (2 * cp2 + 1) * 16 + l16];
        #pragma unroll
        for (int rt = 0; rt < 4; ++rt)
            #pragma unroll
            for (int r = 0; r < 4; ++r) {
                const float h0 = fmaxf((accA[rt][2 * cp2][r]     - mu[rt][r]) * rs[rt][r] * g0v + b0v, 0.f);
                const float h1 = fmaxf((accA[rt][2 * cp2 + 1][r] - mu[rt][r]) * rs[rt][r] * g1v + b1v, 0.f);
                const int row = rt * 16 + l4 + r;
                *(unsigned*)&XC[row][SW(row, nAC + cp2 * 32 + 2 * l16)] = pkbf(h0, h1);
            }
    }
    __syncthreads();   // (3) H ready

    // ---- ep prefetch (flies under fused B+D region) ----
    float ep[4][2][4];
    #pragma unroll
    for (int rt = 0; rt < 4; ++rt)
        #pragma unroll
        for (int ct = 0; ct < 2; ++ct)
            #pragma unroll
            for (int r = 0; r < 4; ++r)
                ep[rt][ct][r] = emb[(size_t)(g0 + rt * 16 + l4 + r) * DD + nBD + ct * 16 + l16];

    // ======== FUSED region 2: B (H@W2 -> accB) + D (R@Wg2 -> accD) ========
    f32x4 accB[4][2], accD[4][2];
    #pragma unroll
    for (int rt = 0; rt < 4; ++rt) {
        accB[rt][0] = zf; accB[rt][1] = zf;
        accD[rt][0] = zf; accD[rt][1] = zf;
    }
    #pragma unroll
    for (int ct = 0; ct < 2; ++ct) {
        {   // B sub-batch
            bfrag wb[8];
            #pragma unroll
            for (int ks = 0; ks < 8; ++ks)
                wb[ks] = *(const bfrag*)(w2t + (size_t)(nBD + ct * 16 + l16) * 256 + ks * 32 + lk8);
            __builtin_amdgcn_sched_barrier(0);
            __builtin_amdgcn_s_setprio(1);
            #pragma unroll
            for (int ks = 0; ks < 8; ++ks) {
                bfrag af[4];
                #pragma unroll
                for (int rt = 0; rt < 4; ++rt)
                    af[rt] = *(const bfrag*)&XC[rt * 16 + l16][SW(l16, ks * 32 + lk8)];
                #pragma unroll
                for (int rt = 0; rt < 4; ++rt)
                    accB[rt][ct] = __builtin_amdgcn_mfma_f32_16x16x32_bf16(af[rt], wb[ks], accB[rt][ct], 0, 0, 0);
            }
            __builtin_amdgcn_s_setprio(0);
        }
        {   // D sub-batch
            bfrag wb[8];
            #pragma unroll
            for (int ks = 0; ks < 8; ++ks)
                wb[ks] = *(const bfrag*)(wg2t + (size_t)(nBD + ct * 16 + l16) * 256 + ks * 32 + lk8);
            __builtin_amdgcn_sched_barrier(0);
            __builtin_amdgcn_s_setprio(1);
            #pragma unroll
            for (int ks = 0; ks < 8; ++ks) {
                bfrag ar[4];
                #pragma unroll
                for (int rt = 0; rt < 4; ++rt)
                    ar[rt] = *(const bfrag*)&Rb[rt * 16 + l16][SW(l16, ks * 32 + lk8)];
                #pragma unroll
                for (int rt = 0; rt < 4; ++rt)
                    accD[rt][ct] = __builtin_amdgcn_mfma_f32_16x16x32_bf16(ar[rt], wb[ks], accD[rt][ct], 0, 0, 0);
            }
            __builtin_amdgcn_s_setprio(0);
        }
    }

    // ================= Epilogue: err, gate, out =================
    #pragma unroll
    for (int ct = 0; ct < 2; ++ct) {
        const float bbB = b2[nBD + ct * 16 + l16];
        const float bbD = bg2[nBD + ct * 16 + l16];
        #pragma unroll
        for (int rt = 0; rt < 4; ++rt)
            #pragma unroll
            for (int r = 0; r < 4; ++r) {
                const float err  = ep[rt][ct][r] - (accB[rt][ct][r] + bbB);
                const float z    = accD[rt][ct][r] + bbD;
                const float gate = 1.f / (1.f + __expf(-z));
                const float ov   = cp[rt][ct][r] + LRATE * gate * err;
                const size_t idx = (size_t)(g0 + rt * 16 + l4 + r) * DD + nBD + ct * 16 + l16;
                if (BOUT) ((u16*)outv)[idx] = f2bf(ov);
                else      ((float*)outv)[idx] = ov;
            }
    }
}

extern "C" void kernel_launch(void* const* d_in, const int* in_sizes, int n_in,
                              void* d_out, int out_size, void* d_ws, size_t ws_size,
                              hipStream_t stream) {
    const float* emb = (const float*)d_in[0];
    const float* W1  = (const float*)d_in[1];
    const float* b1  = (const float*)d_in[2];
    const float* lng = (const float*)d_in[3];
    const float* lnb = (const float*)d_in[4];
    const float* W2  = (const float*)d_in[5];
    const float* b2  = (const float*)d_in[6];
    const float* Wg1 = (const float*)d_in[7];
    const float* bg1 = (const float*)d_in[8];
    const float* Wg2 = (const float*)d_in[9];
    const float* bg2 = (const float*)d_in[10];

    u16* wsw = (u16*)d_ws;                             // 320 KB bf16 transposed weights
    u16* sb0 = (u16*)((char*)d_ws + (1 << 20));        // 32 MB bf16 state ping
    u16* sb1 = sb0 + (size_t)NTOK * DD;                // 32 MB bf16 state pong

    const u16* w1t  = wsw;
    const u16* w2t  = wsw + 32768;
    const u16* wg1t = wsw + 65536;
    const u16* wg2t = wsw + 131072;

    prep_weights<<<640, 256, 0, stream>>>(W1, W2, Wg1, Wg2, wsw);

    const dim3 grid(NTOK / TM);
    const dim3 block(THREADS);
    // refined chain: emb(f32) -> sb0 -> sb1 -> sb0 -> sb1 -> d_out(f32)
    refine_iter<false, true><<<grid, block, 0, stream>>>(emb, emb, sb0,  w1t, w2t, wg1t, wg2t, b1, lng, lnb, b2, bg1, bg2);
    refine_iter<true,  true><<<grid, block, 0, stream>>>(sb0, emb, sb1,  w1t, w2t, wg1t, wg2t, b1, lng, lnb, b2, bg1, bg2);
    refine_iter<true,  true><<<grid, block, 0, stream>>>(sb1, emb, sb0,  w1t, w2t, wg1t, wg2t, b1, lng, lnb, b2, bg1, bg2);
    refine_iter<true,  true><<<grid, block, 0, stream>>>(sb0, emb, sb1,  w1t, w2t, wg1t, wg2t, b1, lng, lnb, b2, bg1, bg2);
    refine_iter<true, false><<<grid, block, 0, stream>>>(sb1, emb, d_out, w1t, w2t, wg1t, wg2t, b1, lng, lnb, b2, bg1, bg2);
}

// Round 28
// 535.942 us; speedup vs baseline: 1.0623x; 1.0623x over previous
//
#include <hip/hip_runtime.h>
#include <hip/hip_bf16.h>

#define BB   16
#define SS   8192
#define DD   128
#define HH   256
#define NTOK (BB * SS)
#define TM   64
#define THREADS 256
#define LRATE 0.1f
#define EPSV  1e-5f
#define XCST 264   // XC stride in shorts
#define RST  264   // Rb stride

typedef short  bfrag __attribute__((ext_vector_type(8)));
typedef float  f32x4 __attribute__((ext_vector_type(4)));
typedef unsigned short u16;

__device__ __forceinline__ u16 f2bf(float x) {
    unsigned u = __float_as_uint(x);
    unsigned r = (u + 0x7FFFu + ((u >> 16) & 1u)) >> 16;   // RTN-even
    return (u16)r;
}
__device__ __forceinline__ unsigned pkbf(float lo, float hi) {
    __hip_bfloat162 h2 = __float22bfloat162_rn(make_float2(lo, hi));
    unsigned u; __builtin_memcpy(&u, &h2, 4); return u;
}
__device__ __forceinline__ float blo(unsigned u) { return __uint_as_float(u << 16); }
__device__ __forceinline__ float bhi(unsigned u) { return __uint_as_float(u & 0xffff0000u); }
__device__ __forceinline__ float b2f(u16 u)      { return __uint_as_float((unsigned)u << 16); }
__device__ __forceinline__ unsigned avgpk(unsigned a, unsigned b) {
    return pkbf(0.5f * (blo(a) + blo(b)), 0.5f * (bhi(a) + bhi(b)));
}

// ---- weight prep: fp32 [K][N] -> bf16 transposed [N][K]; W2t/Wg2t K-permuted within 32-groups ----
__global__ void prep_weights(const float* __restrict__ W1, const float* __restrict__ W2,
                             const float* __restrict__ Wg1, const float* __restrict__ Wg2,
                             u16* __restrict__ wsw) {
    int i = blockIdx.x * 256 + threadIdx.x;   // 0 .. 163839
    if (i < 32768) { int n = i >> 7, k = i & 127; wsw[i] = f2bf(W1[k * 256 + n]); return; }
    i -= 32768;
    if (i < 32768) {
        int n = i >> 8, k = i & 255;
        int m = k & 31;
        int kl = (k & ~31) | ((m & 1) ? ((m >> 1) + 16) : (m >> 1));
        wsw[32768 + n * 256 + k] = f2bf(W2[kl * 128 + n]);
        return;
    }
    i -= 32768;
    if (i < 65536) { int n = i >> 8, k = i & 255; wsw[65536 + n * 256 + k] = f2bf(Wg1[k * 256 + n]); return; }
    i -= 65536;
    {
        int n = i >> 8, k = i & 255;
        int m = k & 31;
        int kl = (k & ~31) | ((m & 1) ? ((m >> 1) + 16) : (m >> 1));
        wsw[131072 + n * 256 + k] = f2bf(Wg2[kl * 128 + n]);
    }
}

template<bool BIN, bool BOUT>
__global__ __launch_bounds__(THREADS, 2)
void refine_iter(const void* __restrict__ curv, const float* __restrict__ emb,
                 void* __restrict__ outv,
                 const u16* __restrict__ w1t, const u16* __restrict__ w2t,
                 const u16* __restrict__ wg1t, const u16* __restrict__ wg2t,
                 const float* __restrict__ b1, const float* __restrict__ lng,
                 const float* __restrict__ lnb, const float* __restrict__ b2,
                 const float* __restrict__ bg1, const float* __restrict__ bg2)
{
    const float* curf = (const float*)curv;
    const u16*   curb = (const u16*)curv;

    __shared__ __align__(16) u16 XC[TM][XCST];   // [x|ctx] -> H (K-permuted)
    __shared__ __align__(16) u16 Rb[TM][RST];    // R (K-permuted), written early
    __shared__ float red1[TM][4];
    __shared__ float red2[TM][4];

    const int t    = threadIdx.x;
    const int nwg  = (int)gridDim.x;
    const int cpx  = nwg >> 3;
    const int bid  = (int)blockIdx.x;
    const int swz  = (bid & 7) * cpx + (bid >> 3);
    const int g0   = swz * TM;
    const int lane = t & 63;
    const int wid  = t >> 6;
    const int l16  = lane & 15;
    const int lk8  = (lane >> 4) * 8;
    const int l4   = (lane >> 4) * 4;
    const int nAC  = wid * 64;
    const int nBD  = wid * 32;

    // ---- stage x tile + context tile, 8 shorts/lane/iter ----
    #pragma unroll
    for (int k = 0; k < 4; ++k) {
        const int f = t + k * THREADS;
        const int m = f >> 4;
        const int o = (f & 15) * 8;
        const int gt = g0 + m;
        const int s  = gt & (SS - 1);
        const int rowbase = gt - s;
        const int sp = (s == 0) ? 1 : s - 1;
        const int sn = (s == SS - 1) ? (SS - 2) : s + 1;
        if (BIN) {
            const uint4 xq = *(const uint4*)(curb + (size_t)gt * DD + o);
            *(uint4*)&XC[m][o] = xq;                      // pure copy, no cvt
            const uint4 aq = *(const uint4*)(curb + (size_t)(rowbase + sp) * DD + o);
            const uint4 bq = *(const uint4*)(curb + (size_t)(rowbase + sn) * DD + o);
            uint4 cq;
            cq.x = avgpk(aq.x, bq.x); cq.y = avgpk(aq.y, bq.y);
            cq.z = avgpk(aq.z, bq.z); cq.w = avgpk(aq.w, bq.w);
            *(uint4*)&XC[m][128 + o] = cq;
        } else {
            const float4 xv0 = *(const float4*)(curf + (size_t)gt * DD + o);
            const float4 xv1 = *(const float4*)(curf + (size_t)gt * DD + o + 4);
            const float4 av0 = *(const float4*)(curf + (size_t)(rowbase + sp) * DD + o);
            const float4 av1 = *(const float4*)(curf + (size_t)(rowbase + sp) * DD + o + 4);
            const float4 bv0 = *(const float4*)(curf + (size_t)(rowbase + sn) * DD + o);
            const float4 bv1 = *(const float4*)(curf + (size_t)(rowbase + sn) * DD + o + 4);
            uint4 xq;
            xq.x = pkbf(xv0.x, xv0.y); xq.y = pkbf(xv0.z, xv0.w);
            xq.z = pkbf(xv1.x, xv1.y); xq.w = pkbf(xv1.z, xv1.w);
            *(uint4*)&XC[m][o] = xq;
            uint4 cq;
            cq.x = pkbf(0.5f * (av0.x + bv0.x), 0.5f * (av0.y + bv0.y));
            cq.y = pkbf(0.5f * (av0.z + bv0.z), 0.5f * (av0.w + bv0.w));
            cq.z = pkbf(0.5f * (av1.x + bv1.x), 0.5f * (av1.y + bv1.y));
            cq.w = pkbf(0.5f * (av1.z + bv1.z), 0.5f * (av1.w + bv1.w));
            *(uint4*)&XC[m][128 + o] = cq;
        }
    }
    __syncthreads();   // (1) stage barrier

    // ---- cp from LDS x-region (MUST be before barrier 2: H overwrites these cols after it) ----
    float cp[4][2][4];
    #pragma unroll
    for (int rt = 0; rt < 4; ++rt)
        #pragma unroll
        for (int ct = 0; ct < 2; ++ct)
            #pragma unroll
            for (int r = 0; r < 4; ++r)
                cp[rt][ct][r] = b2f(XC[rt * 16 + l4 + r][nBD + ct * 16 + l16]);

    const f32x4 zf = {0.f, 0.f, 0.f, 0.f};
    float mu[4][4], rs[4][4];

    // ======== FUSED region 1: A (X@W1 -> accA) + C ([X|C]@Wg1 -> R early) ========
    f32x4 accA[4][4];
    #pragma unroll
    for (int rt = 0; rt < 4; ++rt)
        #pragma unroll
        for (int ct = 0; ct < 4; ++ct) accA[rt][ct] = zf;

    #pragma unroll
    for (int h = 0; h < 2; ++h) {
        bfrag wb[8];
        #pragma unroll
        for (int i = 0; i < 2; ++i)
            #pragma unroll
            for (int ks = 0; ks < 4; ++ks)
                wb[i * 4 + ks] = *(const bfrag*)(w1t + (size_t)(nAC + (h * 2 + i) * 16 + l16) * 128 + ks * 32 + lk8);
        __builtin_amdgcn_sched_barrier(0);
        __builtin_amdgcn_s_setprio(1);
        #pragma unroll
        for (int ks = 0; ks < 4; ++ks) {
            bfrag af[4];
            #pragma unroll
            for (int rt = 0; rt < 4; ++rt)
                af[rt] = *(const bfrag*)&XC[rt * 16 + l16][ks * 32 + lk8];
            #pragma unroll
            for (int i = 0; i < 2; ++i)
                #pragma unroll
                for (int rt = 0; rt < 4; ++rt)
                    accA[rt][h * 2 + i] = __builtin_amdgcn_mfma_f32_16x16x32_bf16(af[rt], wb[i * 4 + ks], accA[rt][h * 2 + i], 0, 0, 0);
        }
        __builtin_amdgcn_s_setprio(0);
    }
    #pragma unroll
    for (int h = 0; h < 2; ++h) {
        f32x4 accC[4][2];
        #pragma unroll
        for (int rt = 0; rt < 4; ++rt) { accC[rt][0] = zf; accC[rt][1] = zf; }
        #pragma unroll
        for (int kh = 0; kh < 2; ++kh) {
            bfrag wb[8];
            #pragma unroll
            for (int i = 0; i < 2; ++i)
                #pragma unroll
                for (int ks2 = 0; ks2 < 4; ++ks2)
                    wb[i * 4 + ks2] = *(const bfrag*)(wg1t + (size_t)(nAC + (h * 2 + i) * 16 + l16) * 256 + (kh * 4 + ks2) * 32 + lk8);
            __builtin_amdgcn_sched_barrier(0);
            __builtin_amdgcn_s_setprio(1);
            #pragma unroll
            for (int ks2 = 0; ks2 < 4; ++ks2) {
                const int ks = kh * 4 + ks2;
                bfrag af[4];
                #pragma unroll
                for (int rt = 0; rt < 4; ++rt)
                    af[rt] = *(const bfrag*)&XC[rt * 16 + l16][ks * 32 + lk8];
                #pragma unroll
                for (int i = 0; i < 2; ++i)
                    #pragma unroll
                    for (int rt = 0; rt < 4; ++rt)
                        accC[rt][i] = __builtin_amdgcn_mfma_f32_16x16x32_bf16(af[rt], wb[i * 4 + ks2], accC[rt][i], 0, 0, 0);
            }
            __builtin_amdgcn_s_setprio(0);
        }
        const float bga = bg1[nAC + (h * 2) * 16 + l16];
        const float bgb = bg1[nAC + (h * 2 + 1) * 16 + l16];
        #pragma unroll
        for (int rt = 0; rt < 4; ++rt)
            #pragma unroll
            for (int r = 0; r < 4; ++r) {
                const float r0v = fmaxf(accC[rt][0][r] + bga, 0.f);
                const float r1v = fmaxf(accC[rt][1][r] + bgb, 0.f);
                *(unsigned*)&Rb[rt * 16 + l4 + r][nAC + h * 32 + 2 * l16] = pkbf(r0v, r1v);
            }
    }

    // ---- bias + LN stats on accA ----
    #pragma unroll
    for (int ct = 0; ct < 4; ++ct) {
        const float bb = b1[nAC + ct * 16 + l16];
        #pragma unroll
        for (int rt = 0; rt < 4; ++rt)
            #pragma unroll
            for (int r = 0; r < 4; ++r) accA[rt][ct][r] += bb;
    }
    #pragma unroll
    for (int rt = 0; rt < 4; ++rt)
        #pragma unroll
        for (int r = 0; r < 4; ++r) {
            float a = 0.f, q = 0.f;
            #pragma unroll
            for (int ct = 0; ct < 4; ++ct) {
                const float v = accA[rt][ct][r];
                a += v; q += v * v;
            }
            #pragma unroll
            for (int m = 1; m <= 8; m <<= 1) {
                a += __shfl_xor(a, m);
                q += __shfl_xor(q, m);
            }
            if (l16 == 0) {
                red1[rt * 16 + l4 + r][wid] = a;
                red2[rt * 16 + l4 + r][wid] = q;
            }
        }
    __syncthreads();   // (2) LN barrier
    #pragma unroll
    for (int rt = 0; rt < 4; ++rt)
        #pragma unroll
        for (int r = 0; r < 4; ++r) {
            const int row = rt * 16 + l4 + r;
            const float4 s1v = *(const float4*)&red1[row][0];
            const float4 s2v = *(const float4*)&red2[row][0];
            const float s1 = s1v.x + s1v.y + s1v.z + s1v.w;
            const float s2 = s2v.x + s2v.y + s2v.z + s2v.w;
            const float m_ = s1 * (1.f / (float)HH);
            mu[rt][r] = m_;
            rs[rt][r] = rsqrtf(s2 * (1.f / (float)HH) - m_ * m_ + EPSV);
        }

    // ---- write H -> XC, K-permuted single u32 store ----
    #pragma unroll
    for (int cp2 = 0; cp2 < 2; ++cp2) {
        const float g0v = lng[nAC + (2 * cp2) * 16 + l16],     b0v = lnb[nAC + (2 * cp2) * 16 + l16];
        const float g1v = lng[nAC + (2 * cp2 + 1) * 16 + l16], b1v = lnb[nAC + (2 * cp2 + 1) * 16 + l16];
        #pragma unroll
        for (int rt = 0; rt < 4; ++rt)
            #pragma unroll
            for (int r = 0; r < 4; ++r) {
                const float h0 = fmaxf((accA[rt][2 * cp2][r]     - mu[rt][r]) * rs[rt][r] * g0v + b0v, 0.f);
                const float h1 = fmaxf((accA[rt][2 * cp2 + 1][r] - mu[rt][r]) * rs[rt][r] * g1v + b1v, 0.f);
                *(unsigned*)&XC[rt * 16 + l4 + r][nAC + cp2 * 32 + 2 * l16] = pkbf(h0, h1);
            }
    }
    __syncthreads();   // (3) H ready

    // ---- ep prefetch (flies under fused B+D region) ----
    float ep[4][2][4];
    #pragma unroll
    for (int rt = 0; rt < 4; ++rt)
        #pragma unroll
        for (int ct = 0; ct < 2; ++ct)
            #pragma unroll
            for (int r = 0; r < 4; ++r)
                ep[rt][ct][r] = emb[(size_t)(g0 + rt * 16 + l4 + r) * DD + nBD + ct * 16 + l16];

    // ======== FUSED region 2: B (H@W2 -> accB) + D (R@Wg2 -> accD) ========
    f32x4 accB[4][2], accD[4][2];
    #pragma unroll
    for (int rt = 0; rt < 4; ++rt) {
        accB[rt][0] = zf; accB[rt][1] = zf;
        accD[rt][0] = zf; accD[rt][1] = zf;
    }
    #pragma unroll
    for (int ct = 0; ct < 2; ++ct) {
        {   // B sub-batch
            bfrag wb[8];
            #pragma unroll
            for (int ks = 0; ks < 8; ++ks)
                wb[ks] = *(const bfrag*)(w2t + (size_t)(nBD + ct * 16 + l16) * 256 + ks * 32 + lk8);
            __builtin_amdgcn_sched_barrier(0);
            __builtin_amdgcn_s_setprio(1);
            #pragma unroll
            for (int ks = 0; ks < 8; ++ks) {
                bfrag af[4];
                #pragma unroll
                for (int rt = 0; rt < 4; ++rt)
                    af[rt] = *(const bfrag*)&XC[rt * 16 + l16][ks * 32 + lk8];
                #pragma unroll
                for (int rt = 0; rt < 4; ++rt)
                    accB[rt][ct] = __builtin_amdgcn_mfma_f32_16x16x32_bf16(af[rt], wb[ks], accB[rt][ct], 0, 0, 0);
            }
            __builtin_amdgcn_s_setprio(0);
        }
        {   // D sub-batch
            bfrag wb[8];
            #pragma unroll
            for (int ks = 0; ks < 8; ++ks)
                wb[ks] = *(const bfrag*)(wg2t + (size_t)(nBD + ct * 16 + l16) * 256 + ks * 32 + lk8);
            __builtin_amdgcn_sched_barrier(0);
            __builtin_amdgcn_s_setprio(1);
            #pragma unroll
            for (int ks = 0; ks < 8; ++ks) {
                bfrag ar[4];
                #pragma unroll
                for (int rt = 0; rt < 4; ++rt)
                    ar[rt] = *(const bfrag*)&Rb[rt * 16 + l16][ks * 32 + lk8];
                #pragma unroll
                for (int rt = 0; rt < 4; ++rt)
                    accD[rt][ct] = __builtin_amdgcn_mfma_f32_16x16x32_bf16(ar[rt], wb[ks], accD[rt][ct], 0, 0, 0);
            }
            __builtin_amdgcn_s_setprio(0);
        }
    }

    // ================= Epilogue: err, gate, out =================
    #pragma unroll
    for (int ct = 0; ct < 2; ++ct) {
        const float bbB = b2[nBD + ct * 16 + l16];
        const float bbD = bg2[nBD + ct * 16 + l16];
        #pragma unroll
        for (int rt = 0; rt < 4; ++rt)
            #pragma unroll
            for (int r = 0; r < 4; ++r) {
                const float err  = ep[rt][ct][r] - (accB[rt][ct][r] + bbB);
                const float z    = accD[rt][ct][r] + bbD;
                const float gate = 1.f / (1.f + __expf(-z));
                const float ov   = cp[rt][ct][r] + LRATE * gate * err;
                const size_t idx = (size_t)(g0 + rt * 16 + l4 + r) * DD + nBD + ct * 16 + l16;
                if (BOUT) ((u16*)outv)[idx] = f2bf(ov);
                else      ((float*)outv)[idx] = ov;
            }
    }
}

extern "C" void kernel_launch(void* const* d_in, const int* in_sizes, int n_in,
                              void* d_out, int out_size, void* d_ws, size_t ws_size,
                              hipStream_t stream) {
    const float* emb = (const float*)d_in[0];
    const float* W1  = (const float*)d_in[1];
    const float* b1  = (const float*)d_in[2];
    const float* lng = (const float*)d_in[3];
    const float* lnb = (const float*)d_in[4];
    const float* W2  = (const float*)d_in[5];
    const float* b2  = (const float*)d_in[6];
    const float* Wg1 = (const float*)d_in[7];
    const float* bg1 = (const float*)d_in[8];
    const float* Wg2 = (const float*)d_in[9];
    const float* bg2 = (const float*)d_in[10];

    u16* wsw = (u16*)d_ws;                             // 320 KB bf16 transposed weights
    u16* sb0 = (u16*)((char*)d_ws + (1 << 20));        // 32 MB bf16 state ping
    u16* sb1 = sb0 + (size_t)NTOK * DD;                // 32 MB bf16 state pong

    const u16* w1t  = wsw;
    const u16* w2t  = wsw + 32768;
    const u16* wg1t = wsw + 65536;
    const u16* wg2t = wsw + 131072;

    prep_weights<<<640, 256, 0, stream>>>(W1, W2, Wg1, Wg2, wsw);

    const dim3 grid(NTOK / TM);
    const dim3 block(THREADS);
    // refined chain: emb(f32) -> sb0 -> sb1 -> sb0 -> sb1 -> d_out(f32)
    refine_iter<false, true><<<grid, block, 0, stream>>>(emb, emb, sb0,  w1t, w2t, wg1t, wg2t, b1, lng, lnb, b2, bg1, bg2);
    refine_iter<true,  true><<<grid, block, 0, stream>>>(sb0, emb, sb1,  w1t, w2t, wg1t, wg2t, b1, lng, lnb, b2, bg1, bg2);
    refine_iter<true,  true><<<grid, block, 0, stream>>>(sb1, emb, sb0,  w1t, w2t, wg1t, wg2t, b1, lng, lnb, b2, bg1, bg2);
    refine_iter<true,  true><<<grid, block, 0, stream>>>(sb0, emb, sb1,  w1t, w2t, wg1t, wg2t, b1, lng, lnb, b2, bg1, bg2);
    refine_iter<true, false><<<grid, block, 0, stream>>>(sb1, emb, d_out, w1t, w2t, wg1t, wg2t, b1, lng, lnb, b2, bg1, bg2);
}